// Round 6
// baseline (366.033 us; speedup 1.0000x reference)
//
#include <hip/hip_runtime.h>
#include <math.h>

#define NQ 131072
#define MN 8192
#define NINT 1024          // internal nodes: 8*i+1 < 8192 -> i <= 1023
#define DEPTHT 16
#define EPSD 1e-6f
#define BIGD 1e9f

// ---------------------------------------------------------------------------
// Kernel 0: transpose W2 [k][j] -> W2T [j][k] (contiguous rows for s_load).
// ---------------------------------------------------------------------------
__global__ __launch_bounds__(256) void transpose_w2(
    const float* __restrict__ W2, float* __restrict__ W2T)
{
    const int i = blockIdx.x * 256 + threadIdx.x;
    if (i < 100 * 100) {
        const int k = i / 100, j = i - k * 100;
        W2T[j * 100 + k] = W2[i];
    }
}

// ---------------------------------------------------------------------------
// Kernel 1: MLP 2 -> 100 -> 100 -> 30 -> 2.
// PIPELINE k-split with BIT-IDENTICAL dataflow to the round-4 kernel (which
// passed): round 5 proved changing the layer-2 FP association flips traversal
// paths (chaotic). Here a thread PAIR serves one row: half 0 runs the round-4
// even/odd chains for k=0..49 and hands the partial chain STATE through LDS;
// half 1 CONTINUES the same chains for k=50..99, then h2j/h3/layer4 exactly
// as round 4. Every FMA has the same operands in the same order -> qx/emb
// bits match round 4. Threads 2x: 4352 waves -> 4.25/SIMD (round 4: 2.1),
// hiding the s_load latency that left round 4 65% stalled.
// Handoff: 2 barriers per chunk (write-after-read provably safe).
// part stride 21 floats (odd) -> worst 2-way LDS bank aliasing (free, m136).
// ---------------------------------------------------------------------------
__global__ __launch_bounds__(256, 4) void mlp_kernel(
    const float* __restrict__ x, const float* __restrict__ nd,
    const float* __restrict__ W1, const float* __restrict__ b1,
    const float* __restrict__ W2T, const float* __restrict__ b2,
    const float* __restrict__ W3, const float* __restrict__ b3,
    const float* __restrict__ W4, const float* __restrict__ b4,
    float* __restrict__ outv)
{
    __shared__ float part[128][21];   // 10.5 KB; [row][j<10]=a0p, [row][10+j]=a1p

    const int tid  = threadIdx.x;
    const int half = tid >> 7;                  // wave-uniform (waves 0,1 | 2,3)
    const int rl   = tid & 127;                 // local row
    const int r    = blockIdx.x * 128 + rl;     // 1088*128 = 139264 exact

    const float2 xi = (r < NQ) ? ((const float2*)x)[r]
                               : ((const float2*)nd)[r - NQ];

    // ---- layer 1: this half's 50 h1 values (same formula as round 4) ----
    float h1[50];
    const int k0 = half * 50;
#pragma unroll
    for (int kk = 0; kk < 50; ++kk)
        h1[kk] = fmaxf(fmaf(xi.x, W1[k0 + kk],
                       fmaf(xi.y, W1[100 + k0 + kk], b1[k0 + kk])), 0.0f);

    float h3[30];
    if (half) {
#pragma unroll
        for (int jj = 0; jj < 30; ++jj) h3[jj] = b3[jj];
    }

    float a0p[10], a1p[10];
    for (int s = 0; s <= 10; ++s) {
        // phase 1a: half 0 computes chunk s chain-prefixes into registers
        if (half == 0 && s < 10) {
            const int jb = s * 10;
#pragma unroll
            for (int j = 0; j < 10; ++j) {
                const float* w2 = W2T + (jb + j) * 100;      // s_load stream
                float a0 = 0.0f, a1 = 0.0f;
#pragma unroll
                for (int k = 0; k < 50; k += 2) {            // round-4 order
                    a0 = fmaf(h1[k],     w2[k],     a0);
                    a1 = fmaf(h1[k + 1], w2[k + 1], a1);
                }
                a0p[j] = a0; a1p[j] = a1;
            }
        }
        // phase 1b: half 1 consumes chunk s-1 (written at end of step s-1)
        if (half == 1 && s > 0) {
            const int jb = (s - 1) * 10;
#pragma unroll
            for (int j = 0; j < 10; ++j) {
                const float* w2 = W2T + (jb + j) * 100;      // s_load stream
                float a0 = part[rl][j];
                float a1 = part[rl][10 + j];
#pragma unroll
                for (int k = 50; k < 100; k += 2) {          // chain continues
                    a0 = fmaf(h1[k - 50], w2[k],     a0);
                    a1 = fmaf(h1[k - 49], w2[k + 1], a1);
                }
                const float h2j = fmaxf(a0 + a1 + b2[jb + j], 0.0f); // verbatim
                const float* w3 = W3 + (jb + j) * 30;
#pragma unroll
                for (int jj = 0; jj < 30; ++jj)
                    h3[jj] = fmaf(h2j, w3[jj], h3[jj]);      // verbatim
            }
        }
        __syncthreads();   // half-1 reads of s-1 done; safe to overwrite
        if (half == 0 && s < 10) {
#pragma unroll
            for (int j = 0; j < 10; ++j) {
                part[rl][j]      = a0p[j];
                part[rl][10 + j] = a1p[j];
            }
        }
        __syncthreads();   // writes visible before next step's reads
    }

    // ---- layer 4: verbatim round 4, owned entirely by half 1 ----
    if (half == 1) {
        float o0 = b4[0], o1 = b4[1];
#pragma unroll
        for (int k = 0; k < 30; ++k) {
            const float h = fmaxf(h3[k], 0.0f);
            o0 = fmaf(h, W4[2 * k],     o0);
            o1 = fmaf(h, W4[2 * k + 1], o1);
        }
        ((float2*)outv)[r] = make_float2(o0, o1);
    }
}

// ---------------------------------------------------------------------------
// Kernel 2: per-internal-node stop-branch class mixture (query-independent).
// Identical formulas/order as rounds 2-3 (passed) -> identical values.
// ---------------------------------------------------------------------------
__global__ __launch_bounds__(256) void prob2_kernel(
    const float2* __restrict__ emb, const float2* __restrict__ cls,
    float2* __restrict__ p2)
{
    const int i = blockIdx.x * 256 + threadIdx.x;   // 0..1023
    const float2 ei = emb[i];
    const int base = 8 * i + 1;

    float d2[8];
    float m2 = BIGD;
#pragma unroll
    for (int j = 0; j < 8; ++j) {
        const int c = base + j;
        const bool v = c < MN;
        const float2 ec = emb[v ? c : 0];
        const float dx = ei.x - ec.x + EPSD;
        const float dy = ei.y - ec.y + EPSD;
        d2[j] = v ? sqrtf(dx * dx + dy * dy) : BIGD;
        m2 = fminf(m2, d2[j]);
    }
    float s2 = 0.0f, mix0 = 0.0f, mix1 = 0.0f;
#pragma unroll
    for (int j = 0; j < 8; ++j) {
        const float w = expf(m2 - d2[j]);   // exactly 0 for pads
        s2 += w;
        const int c = base + j;
        if (c < MN) {
            const float2 cv = cls[c];
            mix0 = fmaf(w, cv.x, mix0);
            mix1 = fmaf(w, cv.y, mix1);
        }
    }
    mix0 /= s2;
    mix1 /= s2;
    p2[i] = make_float2(logf(fmaxf(mix0, 1e-30f)),
                        logf(fmaxf(mix1, 1e-30f)));
}

// ---------------------------------------------------------------------------
// Kernel 3: per-query traversal (round-3 structure, which passed: emb + p2
// staged to LDS from global; d0 carried across steps).
// ---------------------------------------------------------------------------
__global__ __launch_bounds__(256) void traverse_kernel(
    const float* __restrict__ qx, const float2* __restrict__ emb,
    const float2* __restrict__ p2g, float* __restrict__ out)
{
    __shared__ float2 semb[MN];     // 64 KB
    __shared__ float2 sp2[NINT];    // 8 KB
    {
        const float4* ge = (const float4*)emb;
        float4* se = (float4*)semb;
#pragma unroll
        for (int t = 0; t < 16; ++t)
            se[threadIdx.x + 256 * t] = ge[threadIdx.x + 256 * t];
        const float4* gp = (const float4*)p2g;
        float4* sp = (float4*)sp2;
#pragma unroll
        for (int t = 0; t < 2; ++t)
            sp[threadIdx.x + 256 * t] = gp[threadIdx.x + 256 * t];
    }
    __syncthreads();

    const int qi = blockIdx.x * 256 + threadIdx.x;  // grid = NQ/256
    const float2 qv = ((const float2*)qx)[qi];

    int cur = 0;
    float d0;
    {
        const float2 e0 = semb[0];
        const float dx = e0.x - qv.x + EPSD;
        const float dy = e0.y - qv.y + EPSD;
        d0 = sqrtf(dx * dx + dy * dy);
    }
    float prob = 0.0f, out0 = 0.0f, out1 = 0.0f;
    bool done = false;

    for (int t = 0; t < DEPTHT; ++t) {
        if (__all(done)) break;
        if (!done) {
            const int base = 8 * cur + 1;

            float dc[8];
#pragma unroll
            for (int j = 0; j < 8; ++j) {
                const int c = base + j;
                const bool v = c < MN;
                const float2 e = semb[v ? c : 0];
                const float dx = e.x - qv.x + EPSD;
                const float dy = e.y - qv.y + EPSD;
                dc[j] = v ? sqrtf(dx * dx + dy * dy) : BIGD;
            }

            // argmax(log_softmax(-d)) == first argmin(d)
            float dmin = d0;
            int amax = 0;
#pragma unroll
            for (int j = 0; j < 8; ++j)
                if (dc[j] < dmin) { dmin = dc[j]; amax = j + 1; }

            float s = expf(dmin - d0);
#pragma unroll
            for (int j = 0; j < 8; ++j) s += expf(dmin - dc[j]);
            const float max_prob = -logf(s);
            // quirk: t==0 adds max_prob twice
            const float prob_new = prob + max_prob + ((t == 0) ? max_prob : 0.0f);

            if (amax == 0) {
                if (base < MN) {                  // internal node
                    const float2 pp = sp2[cur];
                    out0 = prob_new + pp.x;
                    out1 = prob_new + pp.y;
                } else {                          // leaf
                    out0 = prob_new;
                    out1 = prob_new;
                }
                done = true;
            } else {
                cur  = base + amax - 1;
                d0   = dmin;                      // child dist == next d0
                prob = prob_new;
            }
        }
    }

    ((float2*)out)[qi] = make_float2(out0, out1);
}

// ---------------------------------------------------------------------------
extern "C" void kernel_launch(void* const* d_in, const int* in_sizes, int n_in,
                              void* d_out, int out_size, void* d_ws, size_t ws_size,
                              hipStream_t stream)
{
    const float* x   = (const float*)d_in[0];
    const float* nd  = (const float*)d_in[1];
    const float* cls = (const float*)d_in[2];
    // d_in[3] (children) unused: complete 8-ary tree, child = 8i+1+j if <8192
    const float* W1 = (const float*)d_in[4];
    const float* b1 = (const float*)d_in[5];
    const float* W2 = (const float*)d_in[6];
    const float* b2 = (const float*)d_in[7];
    const float* W3 = (const float*)d_in[8];
    const float* b3 = (const float*)d_in[9];
    const float* W4 = (const float*)d_in[10];
    const float* b4 = (const float*)d_in[11];

    float* ws   = (float*)d_ws;
    float* qx   = ws;                        // [NQ][2]
    float* embf = ws + 2 * NQ;               // [MN][2]
    float* p2f  = ws + 2 * (NQ + MN);        // [NINT][2]
    float* w2t  = p2f + 2 * NINT;            // [100][100]

    transpose_w2<<<40, 256, 0, stream>>>(W2, w2t);

    mlp_kernel<<<(NQ + MN) / 128, 256, 0, stream>>>(
        x, nd, W1, b1, w2t, b2, W3, b3, W4, b4, qx);

    prob2_kernel<<<NINT / 256, 256, 0, stream>>>(
        (const float2*)embf, (const float2*)cls, (float2*)p2f);

    traverse_kernel<<<NQ / 256, 256, 0, stream>>>(
        qx, (const float2*)embf, (const float2*)p2f, (float*)d_out);
}

// Round 7
// 178.546 us; speedup vs baseline: 2.0501x; 2.0501x over previous
//
#include <hip/hip_runtime.h>
#include <math.h>

#define NQ 131072
#define MN 8192
#define NINT 1024          // internal nodes: 8*i+1 < 8192 -> i <= 1023
#define DEPTHT 16
#define EPSD 1e-6f
#define BIGD 1e9f

// ---------------------------------------------------------------------------
// Kernel 0: transpose W2 [k][j] -> W2T [j][k] (contiguous rows for staging).
// ---------------------------------------------------------------------------
__global__ __launch_bounds__(256) void transpose_w2(
    const float* __restrict__ W2, float* __restrict__ W2T)
{
    const int i = blockIdx.x * 256 + threadIdx.x;
    if (i < 100 * 100) {
        const int k = i / 100, j = i - k * 100;
        W2T[j * 100 + k] = W2[i];
    }
}

// ---------------------------------------------------------------------------
// Kernel 1: MLP 2 -> 100 -> 100 -> 30 -> 2, one row per thread.
// EXACT round-4 per-thread FMA dag (same operands, same order -> bit-identical
// qx/emb; R4 passed). Single change: the big weight streams (W2T 40KB,
// W3 12.8KB) come from LDS at WAVE-UNIFORM addresses (ds_read broadcast,
// conflict-free) instead of s_load. R4 post-mortem: issue time == pure-FMA
// floor (24.9us) but 65% stalled on scalar-cache thrash (52KB streams >> K$,
// ~200cy L2 refills, only 2.1 waves/SIMD to hide them). LDS is resident and
// pipelinable; K$ now holds only W1/b1/b2/W4 (~1.7KB) -> s_loads always hit.
// Straight-line single-loop body (R2/R6 lesson: phases/divergence => spill).
// ---------------------------------------------------------------------------
__global__ __launch_bounds__(256, 2) void mlp_kernel(
    const float* __restrict__ x, const float* __restrict__ nd,
    const float* __restrict__ W1, const float* __restrict__ b1,
    const float* __restrict__ W2T, const float* __restrict__ b2,
    const float* __restrict__ W3, const float* __restrict__ b3,
    const float* __restrict__ W4, const float* __restrict__ b4,
    float* __restrict__ outv)
{
    __shared__ float sW2[100 * 100];   // 40 KB   [j][k]
    __shared__ float sW3[100 * 32];    // 12.8 KB [j][jj<30], stride 32

    const int tid = threadIdx.x;
    {
        const float4* g = (const float4*)W2T;       // 2500 float4, coalesced
        float4* s = (float4*)sW2;
        for (int i = tid; i < 2500; i += 256) s[i] = g[i];
        for (int i = tid; i < 3000; i += 256) {
            const int row = i / 30, col = i - row * 30;
            sW3[row * 32 + col] = W3[i];
        }
    }
    __syncthreads();

    const int r = blockIdx.x * 256 + tid;           // 544*256 = 139264 exact
    const float2 xi = (r < NQ) ? ((const float2*)x)[r]
                               : ((const float2*)nd)[r - NQ];

    // ---- layer 1: h1[100] in VGPRs (verbatim round 4) ----
    float h1[100];
#pragma unroll
    for (int k = 0; k < 100; ++k)
        h1[k] = fmaxf(fmaf(xi.x, W1[k], fmaf(xi.y, W1[100 + k], b1[k])), 0.0f);

    // ---- layers 2+3 fused (verbatim round 4, weights now LDS-uniform) ----
    float h3[30];
#pragma unroll
    for (int jj = 0; jj < 30; ++jj) h3[jj] = b3[jj];

    for (int j = 0; j < 100; ++j) {
        const float* w2 = sW2 + j * 100;            // uniform addr ds_read
        float a0 = 0.0f, a1 = 0.0f;                 // 2 chains (R4 order)
#pragma unroll
        for (int k = 0; k < 100; k += 2) {
            a0 = fmaf(h1[k],     w2[k],     a0);
            a1 = fmaf(h1[k + 1], w2[k + 1], a1);
        }
        const float h2j = fmaxf(a0 + a1 + b2[j], 0.0f);
        const float* w3 = sW3 + j * 32;             // uniform addr ds_read
#pragma unroll
        for (int jj = 0; jj < 30; ++jj)
            h3[jj] = fmaf(h2j, w3[jj], h3[jj]);
    }

    // ---- layer 4: 30 -> 2 (verbatim round 4) ----
    float o0 = b4[0], o1 = b4[1];
#pragma unroll
    for (int k = 0; k < 30; ++k) {
        const float h = fmaxf(h3[k], 0.0f);
        o0 = fmaf(h, W4[2 * k],     o0);
        o1 = fmaf(h, W4[2 * k + 1], o1);
    }
    ((float2*)outv)[r] = make_float2(o0, o1);
}

// ---------------------------------------------------------------------------
// Kernel 2: per-internal-node stop-branch class mixture (query-independent).
// Verbatim round 6 (passed).
// ---------------------------------------------------------------------------
__global__ __launch_bounds__(256) void prob2_kernel(
    const float2* __restrict__ emb, const float2* __restrict__ cls,
    float2* __restrict__ p2)
{
    const int i = blockIdx.x * 256 + threadIdx.x;   // 0..1023
    const float2 ei = emb[i];
    const int base = 8 * i + 1;

    float d2[8];
    float m2 = BIGD;
#pragma unroll
    for (int j = 0; j < 8; ++j) {
        const int c = base + j;
        const bool v = c < MN;
        const float2 ec = emb[v ? c : 0];
        const float dx = ei.x - ec.x + EPSD;
        const float dy = ei.y - ec.y + EPSD;
        d2[j] = v ? sqrtf(dx * dx + dy * dy) : BIGD;
        m2 = fminf(m2, d2[j]);
    }
    float s2 = 0.0f, mix0 = 0.0f, mix1 = 0.0f;
#pragma unroll
    for (int j = 0; j < 8; ++j) {
        const float w = expf(m2 - d2[j]);   // exactly 0 for pads
        s2 += w;
        const int c = base + j;
        if (c < MN) {
            const float2 cv = cls[c];
            mix0 = fmaf(w, cv.x, mix0);
            mix1 = fmaf(w, cv.y, mix1);
        }
    }
    mix0 /= s2;
    mix1 /= s2;
    p2[i] = make_float2(logf(fmaxf(mix0, 1e-30f)),
                        logf(fmaxf(mix1, 1e-30f)));
}

// ---------------------------------------------------------------------------
// Kernel 3: per-query traversal. Verbatim round 6 (passed): emb + p2 staged
// to LDS; d0 carried across steps.
// ---------------------------------------------------------------------------
__global__ __launch_bounds__(256) void traverse_kernel(
    const float* __restrict__ qx, const float2* __restrict__ emb,
    const float2* __restrict__ p2g, float* __restrict__ out)
{
    __shared__ float2 semb[MN];     // 64 KB
    __shared__ float2 sp2[NINT];    // 8 KB
    {
        const float4* ge = (const float4*)emb;
        float4* se = (float4*)semb;
#pragma unroll
        for (int t = 0; t < 16; ++t)
            se[threadIdx.x + 256 * t] = ge[threadIdx.x + 256 * t];
        const float4* gp = (const float4*)p2g;
        float4* sp = (float4*)sp2;
#pragma unroll
        for (int t = 0; t < 2; ++t)
            sp[threadIdx.x + 256 * t] = gp[threadIdx.x + 256 * t];
    }
    __syncthreads();

    const int qi = blockIdx.x * 256 + threadIdx.x;  // grid = NQ/256
    const float2 qv = ((const float2*)qx)[qi];

    int cur = 0;
    float d0;
    {
        const float2 e0 = semb[0];
        const float dx = e0.x - qv.x + EPSD;
        const float dy = e0.y - qv.y + EPSD;
        d0 = sqrtf(dx * dx + dy * dy);
    }
    float prob = 0.0f, out0 = 0.0f, out1 = 0.0f;
    bool done = false;

    for (int t = 0; t < DEPTHT; ++t) {
        if (__all(done)) break;
        if (!done) {
            const int base = 8 * cur + 1;

            float dc[8];
#pragma unroll
            for (int j = 0; j < 8; ++j) {
                const int c = base + j;
                const bool v = c < MN;
                const float2 e = semb[v ? c : 0];
                const float dx = e.x - qv.x + EPSD;
                const float dy = e.y - qv.y + EPSD;
                dc[j] = v ? sqrtf(dx * dx + dy * dy) : BIGD;
            }

            // argmax(log_softmax(-d)) == first argmin(d)
            float dmin = d0;
            int amax = 0;
#pragma unroll
            for (int j = 0; j < 8; ++j)
                if (dc[j] < dmin) { dmin = dc[j]; amax = j + 1; }

            float s = expf(dmin - d0);
#pragma unroll
            for (int j = 0; j < 8; ++j) s += expf(dmin - dc[j]);
            const float max_prob = -logf(s);
            // quirk: t==0 adds max_prob twice
            const float prob_new = prob + max_prob + ((t == 0) ? max_prob : 0.0f);

            if (amax == 0) {
                if (base < MN) {                  // internal node
                    const float2 pp = sp2[cur];
                    out0 = prob_new + pp.x;
                    out1 = prob_new + pp.y;
                } else {                          // leaf
                    out0 = prob_new;
                    out1 = prob_new;
                }
                done = true;
            } else {
                cur  = base + amax - 1;
                d0   = dmin;                      // child dist == next d0
                prob = prob_new;
            }
        }
    }

    ((float2*)out)[qi] = make_float2(out0, out1);
}

// ---------------------------------------------------------------------------
extern "C" void kernel_launch(void* const* d_in, const int* in_sizes, int n_in,
                              void* d_out, int out_size, void* d_ws, size_t ws_size,
                              hipStream_t stream)
{
    const float* x   = (const float*)d_in[0];
    const float* nd  = (const float*)d_in[1];
    const float* cls = (const float*)d_in[2];
    // d_in[3] (children) unused: complete 8-ary tree, child = 8i+1+j if <8192
    const float* W1 = (const float*)d_in[4];
    const float* b1 = (const float*)d_in[5];
    const float* W2 = (const float*)d_in[6];
    const float* b2 = (const float*)d_in[7];
    const float* W3 = (const float*)d_in[8];
    const float* b3 = (const float*)d_in[9];
    const float* W4 = (const float*)d_in[10];
    const float* b4 = (const float*)d_in[11];

    float* ws   = (float*)d_ws;
    float* qx   = ws;                        // [NQ][2]
    float* embf = ws + 2 * NQ;               // [MN][2]
    float* p2f  = ws + 2 * (NQ + MN);        // [NINT][2]
    float* w2t  = p2f + 2 * NINT;            // [100][100]

    transpose_w2<<<40, 256, 0, stream>>>(W2, w2t);

    mlp_kernel<<<(NQ + MN) / 256, 256, 0, stream>>>(
        x, nd, W1, b1, w2t, b2, W3, b3, W4, b4, qx);

    prob2_kernel<<<NINT / 256, 256, 0, stream>>>(
        (const float2*)embf, (const float2*)cls, (float2*)p2f);

    traverse_kernel<<<NQ / 256, 256, 0, stream>>>(
        qx, (const float2*)embf, (const float2*)p2f, (float*)d_out);
}